// Round 17
// baseline (98.327 us; speedup 1.0000x reference)
//
#include <hip/hip_runtime.h>
#include <hip/hip_bf16.h>
#include <cstdint>
#include <cstddef>

#define RANK 16

typedef __attribute__((ext_vector_type(8))) short bf16x8;   // 8 bf16 (4 VGPRs)
typedef __attribute__((ext_vector_type(4))) float f32x4;    // MFMA C/D

static __device__ __forceinline__ short f2bf(float f) {
  __hip_bfloat16 h = __float2bfloat16(f);
  return *reinterpret_cast<short*>(&h);
}

// ---------------------------------------------------------------------------
// Kernel 1: mix LoRA factors with per-(batch,split) skill weights. [unchanged]
//   Amt[b][r][k] = bf16( sum_s w[b][q][s] * la[q][s][d][r] ), k = q*512 + d
//   Bm[b][r][o]  = 2 * sum_s w[b][q][s] * lb[q][s][r][dd],   o = q*512 + dd
// ---------------------------------------------------------------------------
__global__ __launch_bounds__(256) void skilled_lora_mix(
    const float* __restrict__ w,       // [8][4][8]
    const float* __restrict__ la,      // [4][8][512][16]
    const float* __restrict__ lb,      // [4][8][16][512]
    __hip_bfloat16* __restrict__ Amt,  // [8][16][2048] bf16
    float* __restrict__ Bm)            // [8][16][2048] fp32, pre-scaled by 2
{
  const int j = blockIdx.x * 256 + threadIdx.x;
  if (j < 65536) {
    const int r0 = (j & 3) * 4;
    const int k  = (j >> 2) & 2047;
    const int b  = j >> 13;
    const int q  = k >> 9;
    const int d  = k & 511;
    const float* wb = w + (b * 4 + q) * 8;
    float4 acc = make_float4(0.f, 0.f, 0.f, 0.f);
#pragma unroll
    for (int s = 0; s < 8; ++s) {
      const float ws = wb[s];
      const float4 v = *reinterpret_cast<const float4*>(
          la + (size_t)(((q * 8 + s) * 512 + d) * 16 + r0));
      acc.x = fmaf(ws, v.x, acc.x);
      acc.y = fmaf(ws, v.y, acc.y);
      acc.z = fmaf(ws, v.z, acc.z);
      acc.w = fmaf(ws, v.w, acc.w);
    }
    Amt[((size_t)(b * 16 + r0 + 0)) * 2048 + k] = __float2bfloat16(acc.x);
    Amt[((size_t)(b * 16 + r0 + 1)) * 2048 + k] = __float2bfloat16(acc.y);
    Amt[((size_t)(b * 16 + r0 + 2)) * 2048 + k] = __float2bfloat16(acc.z);
    Amt[((size_t)(b * 16 + r0 + 3)) * 2048 + k] = __float2bfloat16(acc.w);
  } else {
    const int jj = j - 65536;
    const int o  = (jj & 511) * 4;
    const int r  = (jj >> 9) & 15;
    const int b  = jj >> 13;
    const int q  = o >> 9;
    const int dd = o & 511;
    const float* wb = w + (b * 4 + q) * 8;
    float4 acc = make_float4(0.f, 0.f, 0.f, 0.f);
#pragma unroll
    for (int s = 0; s < 8; ++s) {
      const float ws = wb[s];
      const float4 v = *reinterpret_cast<const float4*>(
          lb + (size_t)(((q * 8 + s) * 16 + r) * 512 + dd));
      acc.x = fmaf(ws, v.x, acc.x);
      acc.y = fmaf(ws, v.y, acc.y);
      acc.z = fmaf(ws, v.z, acc.z);
      acc.w = fmaf(ws, v.w, acc.w);
    }
    acc.x *= 2.f; acc.y *= 2.f; acc.z *= 2.f; acc.w *= 2.f;
    *reinterpret_cast<float4*>(Bm + (size_t)((b * 16 + r) * 2048 + o)) = acc;
  }
}

// ---------------------------------------------------------------------------
// Kernel 2 (dual-role pipelined): blocks [0, nA*256) run phase A for batches
// [aBase, aBase+nA); blocks [nA*256, nA*256+nB*256) run phase B for batches
// [bBase, bBase+nB).
//
// ROUND-17: read/write direction overlap. Serial structure pays 43us (A,
// read-capped at ~3.0 TB/s = the per-direction rate m13's copy sustains) +
// 19us (B, write floor) sequentially, though m13 proves both directions run
// concurrently. r15's intra-block fusion stayed phase-locked; here the roles
// are split by BLOCK RANGE within one launch, so read-streams (A-blocks) and
// write-streams (B-blocks) are simultaneously resident chip-wide. Stream
// order between launches provides the A->B data dependency (batch pipeline:
// A leads B by 2 batches). Bodies are r16's validated kernels verbatim.
// (256,2): the only launch-bounds that never clamp-spilled; A is occupancy-
// insensitive (r11) so losing its (256,8) cap is safe.
// ---------------------------------------------------------------------------
__global__ __launch_bounds__(256, 2) void lora_pipe(
    const float* __restrict__ X,            // [8][2048][2048]
    const __hip_bfloat16* __restrict__ Amt, // [8][16][2048] bf16
    const float* __restrict__ Bm,           // [8][16][2048] fp32 (pre-scaled)
    float* __restrict__ tmp_p,              // [2][8][2048][16] partials
    float* __restrict__ out,                // [8][2048][2048]
    int aBase, int nA, int bBase, int nB)
{
  __shared__ float lds[4 * 16 * 68];        // 17.4 KB (A-role only)

  const int tid = threadIdx.x;

  if ((int)blockIdx.x < nA * 256) {
    // =============== phase A unit: (batch, 16-row tile, k-split) ===========
    const int u    = blockIdx.x;
    const int lane = tid & 63;
    const int wv   = tid >> 6;               // 0..3: 256-k sub-window
    const int b    = aBase + (u >> 8);       // 256 units per batch
    const int tile = (u >> 1) & 127;
    const int ks   = u & 1;                  // k-split 0..1
    const int row0 = tile * 16;
    const int k0   = ks * 1024 + wv * 256;
    const int m    = lane & 15;              // fragment row / r
    const int g    = lane >> 4;              // k-subgroup 0..3

    float* stage = lds + wv * (16 * 68);     // wave-private [16][68]
    const int ms = lane >> 2;                // staging row 0..15
    const int cs = (lane & 3) * 4;           // staging 16B chunk (floats)

    const float* Xb = X + ((size_t)(b * 2048 + row0)) * 2048 + k0;
    const __hip_bfloat16* Ap = Amt + ((size_t)(b * 16 + m)) * 2048 + k0 + g * 8;

    f32x4 acc = {0.f, 0.f, 0.f, 0.f};

    for (int c = 0; c < 4; ++c) {            // 4 chunks of 64 k
      const int kc = c * 64;
#pragma unroll
      for (int i = 0; i < 4; ++i) {
        const float4 v = *reinterpret_cast<const float4*>(
            Xb + (size_t)ms * 2048 + kc + i * 16 + cs);
        *reinterpret_cast<float4*>(&stage[ms * 68 + i * 16 + cs]) = v;
      }
      // wave-private LDS; compiler inserts vmcnt/lgkmcnt; no barrier.
#pragma unroll
      for (int h = 0; h < 2; ++h) {
        const float4 xlo = *reinterpret_cast<const float4*>(
            &stage[m * 68 + h * 32 + g * 8]);
        const float4 xhi = *reinterpret_cast<const float4*>(
            &stage[m * 68 + h * 32 + g * 8 + 4]);
        bf16x8 afrag;
        afrag[0] = f2bf(xlo.x); afrag[1] = f2bf(xlo.y);
        afrag[2] = f2bf(xlo.z); afrag[3] = f2bf(xlo.w);
        afrag[4] = f2bf(xhi.x); afrag[5] = f2bf(xhi.y);
        afrag[6] = f2bf(xhi.z); afrag[7] = f2bf(xhi.w);
        const bf16x8 bfrag = *reinterpret_cast<const bf16x8*>(
            Ap + (size_t)(c * 2 + h) * 32);
        acc = __builtin_amdgcn_mfma_f32_16x16x32_bf16(afrag, bfrag, acc, 0, 0, 0);
      }
    }

    __syncthreads();                         // all waves done with stage
    float* part = lds;
#pragma unroll
    for (int v = 0; v < 4; ++v)
      part[(wv * 16 + g * 4 + v) * 17 + m] = acc[v];
    __syncthreads();

    const int row = tid >> 4;                // 0..15
    const int r   = tid & 15;
    const float s = part[(0 * 16 + row) * 17 + r] + part[(1 * 16 + row) * 17 + r]
                  + part[(2 * 16 + row) * 17 + r] + part[(3 * 16 + row) * 17 + r];
    tmp_p[((size_t)((ks * 8 + b) * 2048 + row0 + row)) * RANK + r] = s;

  } else {
    // =============== phase B unit: (batch, 32-row tile, 512-col group) =====
    const int u    = blockIdx.x - nA * 256;
    const int b    = bBase + (u >> 8);       // 256 units per batch
    const int rt   = (u >> 2) & 63;          // row tile (32 rows)
    const int og   = u & 3;                  // column group (512 cols)
    const int row0 = rt * 32;
    const int o0   = og * 512 + tid * 2;

    const float* Bb = Bm + (size_t)b * (RANK * 2048) + o0;
    float2 B2[RANK];
#pragma unroll
    for (int r = 0; r < RANK; ++r)
      B2[r] = *reinterpret_cast<const float2*>(Bb + (size_t)r * 2048);

    const float* tp0 = tmp_p + ((size_t)(b * 2048 + row0)) * RANK;
    const float* tp1 = tmp_p + ((size_t)((8 + b) * 2048 + row0)) * RANK;
    float* op = out + ((size_t)(b * 2048 + row0)) * 2048 + o0;

#pragma unroll 4
    for (int rr = 0; rr < 32; ++rr) {
      const float4 u0 = *reinterpret_cast<const float4*>(tp0 + rr * RANK);
      const float4 u1 = *reinterpret_cast<const float4*>(tp0 + rr * RANK + 4);
      const float4 u2 = *reinterpret_cast<const float4*>(tp0 + rr * RANK + 8);
      const float4 u3 = *reinterpret_cast<const float4*>(tp0 + rr * RANK + 12);
      const float4 v0 = *reinterpret_cast<const float4*>(tp1 + rr * RANK);
      const float4 v1 = *reinterpret_cast<const float4*>(tp1 + rr * RANK + 4);
      const float4 v2 = *reinterpret_cast<const float4*>(tp1 + rr * RANK + 8);
      const float4 v3 = *reinterpret_cast<const float4*>(tp1 + rr * RANK + 12);
      const float t0x = u0.x + v0.x, t0y = u0.y + v0.y, t0z = u0.z + v0.z, t0w = u0.w + v0.w;
      const float t1x = u1.x + v1.x, t1y = u1.y + v1.y, t1z = u1.z + v1.z, t1w = u1.w + v1.w;
      const float t2x = u2.x + v2.x, t2y = u2.y + v2.y, t2z = u2.z + v2.z, t2w = u2.w + v2.w;
      const float t3x = u3.x + v3.x, t3y = u3.y + v3.y, t3z = u3.z + v3.z, t3w = u3.w + v3.w;
      float2 a = make_float2(0.f, 0.f);
      a.x = fmaf(t0x, B2[0].x,  a.x);  a.y = fmaf(t0x, B2[0].y,  a.y);
      a.x = fmaf(t0y, B2[1].x,  a.x);  a.y = fmaf(t0y, B2[1].y,  a.y);
      a.x = fmaf(t0z, B2[2].x,  a.x);  a.y = fmaf(t0z, B2[2].y,  a.y);
      a.x = fmaf(t0w, B2[3].x,  a.x);  a.y = fmaf(t0w, B2[3].y,  a.y);
      a.x = fmaf(t1x, B2[4].x,  a.x);  a.y = fmaf(t1x, B2[4].y,  a.y);
      a.x = fmaf(t1y, B2[5].x,  a.x);  a.y = fmaf(t1y, B2[5].y,  a.y);
      a.x = fmaf(t1z, B2[6].x,  a.x);  a.y = fmaf(t1z, B2[6].y,  a.y);
      a.x = fmaf(t1w, B2[7].x,  a.x);  a.y = fmaf(t1w, B2[7].y,  a.y);
      a.x = fmaf(t2x, B2[8].x,  a.x);  a.y = fmaf(t2x, B2[8].y,  a.y);
      a.x = fmaf(t2y, B2[9].x,  a.x);  a.y = fmaf(t2y, B2[9].y,  a.y);
      a.x = fmaf(t2z, B2[10].x, a.x);  a.y = fmaf(t2z, B2[10].y, a.y);
      a.x = fmaf(t2w, B2[11].x, a.x);  a.y = fmaf(t2w, B2[11].y, a.y);
      a.x = fmaf(t3x, B2[12].x, a.x);  a.y = fmaf(t3x, B2[12].y, a.y);
      a.x = fmaf(t3y, B2[13].x, a.x);  a.y = fmaf(t3y, B2[13].y, a.y);
      a.x = fmaf(t3z, B2[14].x, a.x);  a.y = fmaf(t3z, B2[14].y, a.y);
      a.x = fmaf(t3w, B2[15].x, a.x);  a.y = fmaf(t3w, B2[15].y, a.y);
      *reinterpret_cast<float2*>(op + (size_t)rr * 2048) = a;
    }
  }
}

// ---------------------------------------------------------------------------
extern "C" void kernel_launch(void* const* d_in, const int* in_sizes, int n_in,
                              void* d_out, int out_size, void* d_ws, size_t ws_size,
                              hipStream_t stream) {
  const float* input = (const float*)d_in[0];   // [8][2048][2048]
  const float* w     = (const float*)d_in[1];   // [8][4][8]
  const float* la    = (const float*)d_in[2];   // [4][8][512][16]
  const float* lb    = (const float*)d_in[3];   // [4][8][16][512]
  float* outp = (float*)d_out;

  __hip_bfloat16* Amt = (__hip_bfloat16*)d_ws;                      // 512 KB
  float* Bm    = (float*)((char*)d_ws + (size_t)8 * 16 * 2048 * 2); // 1 MB
  float* tmp_p = Bm + 8 * RANK * 2048;                              // 2 MB

  skilled_lora_mix<<<512, 256, 0, stream>>>(w, la, lb, Amt, Bm);

  // Batch-pipelined schedule: A leads B by 2 batches. Stream order between
  // launches provides the dependency; within each dual launch, A-blocks
  // (readers) and B-blocks (writers) are co-resident -> concurrent
  // read+write direction traffic (m13: the chip sustains 3.15+3.15 TB/s).
  lora_pipe<<< 512, 256, 0, stream>>>(input, Amt, Bm, tmp_p, outp, 0, 2, 0, 0);
  lora_pipe<<<1024, 256, 0, stream>>>(input, Amt, Bm, tmp_p, outp, 2, 2, 0, 2);
  lora_pipe<<<1024, 256, 0, stream>>>(input, Amt, Bm, tmp_p, outp, 4, 2, 2, 2);
  lora_pipe<<<1024, 256, 0, stream>>>(input, Amt, Bm, tmp_p, outp, 6, 2, 4, 2);
  lora_pipe<<< 512, 256, 0, stream>>>(input, Amt, Bm, tmp_p, outp, 0, 0, 6, 2);
}

// Round 18
// 65.404 us; speedup vs baseline: 1.5034x; 1.5034x over previous
//
#include <hip/hip_runtime.h>
#include <hip/hip_bf16.h>
#include <cstdint>
#include <cstddef>

#define RANK 16

typedef __attribute__((ext_vector_type(8))) short bf16x8;   // 8 bf16 (4 VGPRs)
typedef __attribute__((ext_vector_type(4))) float f32x4;    // MFMA C/D

static __device__ __forceinline__ short f2bf(float f) {
  __hip_bfloat16 h = __float2bfloat16(f);
  return *reinterpret_cast<short*>(&h);
}

// ---------------------------------------------------------------------------
// ROUND-18: exact revert to the round-16 build (best measured: 65.9 us).
// r17's dual-role pipelining regressed 32 us (per-launch A-parallelism
// collapsed to 2 blocks/CU; overlap showed no net benefit). Direction-
// overlap is falsified twice (r15 phase-locked, r17 role-split); the serial
// 3-launch structure at measured per-direction ceilings (read ~3.05 TB/s,
// write ~7 TB/s) predicts 67 us ~= r16's 65.9.
// ---------------------------------------------------------------------------

// ---------------------------------------------------------------------------
// Kernel 1: mix LoRA factors with per-(batch,split) skill weights.
//   Amt[b][r][k] = bf16( sum_s w[b][q][s] * la[q][s][d][r] ), k = q*512 + d
//   Bm[b][r][o]  = 2 * sum_s w[b][q][s] * lb[q][s][r][dd],   o = q*512 + dd
// ---------------------------------------------------------------------------
__global__ __launch_bounds__(256) void skilled_lora_mix(
    const float* __restrict__ w,       // [8][4][8]
    const float* __restrict__ la,      // [4][8][512][16]
    const float* __restrict__ lb,      // [4][8][16][512]
    __hip_bfloat16* __restrict__ Amt,  // [8][16][2048] bf16
    float* __restrict__ Bm)            // [8][16][2048] fp32, pre-scaled by 2
{
  const int j = blockIdx.x * 256 + threadIdx.x;
  if (j < 65536) {
    const int r0 = (j & 3) * 4;
    const int k  = (j >> 2) & 2047;
    const int b  = j >> 13;
    const int q  = k >> 9;
    const int d  = k & 511;
    const float* wb = w + (b * 4 + q) * 8;
    float4 acc = make_float4(0.f, 0.f, 0.f, 0.f);
#pragma unroll
    for (int s = 0; s < 8; ++s) {
      const float ws = wb[s];
      const float4 v = *reinterpret_cast<const float4*>(
          la + (size_t)(((q * 8 + s) * 512 + d) * 16 + r0));
      acc.x = fmaf(ws, v.x, acc.x);
      acc.y = fmaf(ws, v.y, acc.y);
      acc.z = fmaf(ws, v.z, acc.z);
      acc.w = fmaf(ws, v.w, acc.w);
    }
    Amt[((size_t)(b * 16 + r0 + 0)) * 2048 + k] = __float2bfloat16(acc.x);
    Amt[((size_t)(b * 16 + r0 + 1)) * 2048 + k] = __float2bfloat16(acc.y);
    Amt[((size_t)(b * 16 + r0 + 2)) * 2048 + k] = __float2bfloat16(acc.z);
    Amt[((size_t)(b * 16 + r0 + 3)) * 2048 + k] = __float2bfloat16(acc.w);
  } else {
    const int jj = j - 65536;
    const int o  = (jj & 511) * 4;
    const int r  = (jj >> 9) & 15;
    const int b  = jj >> 13;
    const int q  = o >> 9;
    const int dd = o & 511;
    const float* wb = w + (b * 4 + q) * 8;
    float4 acc = make_float4(0.f, 0.f, 0.f, 0.f);
#pragma unroll
    for (int s = 0; s < 8; ++s) {
      const float ws = wb[s];
      const float4 v = *reinterpret_cast<const float4*>(
          lb + (size_t)(((q * 8 + s) * 16 + r) * 512 + dd));
      acc.x = fmaf(ws, v.x, acc.x);
      acc.y = fmaf(ws, v.y, acc.y);
      acc.z = fmaf(ws, v.z, acc.z);
      acc.w = fmaf(ws, v.w, acc.w);
    }
    acc.x *= 2.f; acc.y *= 2.f; acc.z *= 2.f; acc.w *= 2.f;
    *reinterpret_cast<float4*>(Bm + (size_t)((b * 16 + r) * 2048 + o)) = acc;
  }
}

// ---------------------------------------------------------------------------
// Kernel 2 (phase A): staged wave-private LDS, coalesced b128 staging,
// (256,8), grid 2048 = 8b x 128 tiles x 2 k-splits. Runs at ~2.9 TB/s read
// = ~95% of the observed per-direction read ceiling.
// ---------------------------------------------------------------------------
__global__ __launch_bounds__(256, 8) void lora_phase_a(
    const float* __restrict__ X,           // [8][2048][2048]
    const __hip_bfloat16* __restrict__ Amt,// [8][16][2048] bf16
    float* __restrict__ tmp_p)             // [2][8][2048][16] partials
{
  __shared__ float lds[4 * 16 * 68];       // 17.4 KB

  const int tid  = threadIdx.x;
  const int lane = tid & 63;
  const int wv   = tid >> 6;               // 0..3: 256-k sub-window
  const int b    = blockIdx.x >> 8;        // 8 batches
  const int tile = (blockIdx.x >> 1) & 127;
  const int ks   = blockIdx.x & 1;         // k-split 0..1
  const int row0 = tile * 16;
  const int k0   = ks * 1024 + wv * 256;
  const int m    = lane & 15;              // fragment row / r
  const int g    = lane >> 4;              // k-subgroup 0..3

  float* stage = lds + wv * (16 * 68);     // wave-private [16][68]

  const int ms = lane >> 2;                // staging row 0..15
  const int cs = (lane & 3) * 4;           // staging 16B chunk (floats)

  const float* Xb = X + ((size_t)(b * 2048 + row0)) * 2048 + k0;
  const __hip_bfloat16* Ap = Amt + ((size_t)(b * 16 + m)) * 2048 + k0 + g * 8;

  f32x4 acc = {0.f, 0.f, 0.f, 0.f};

  for (int c = 0; c < 4; ++c) {            // 4 chunks of 64 k
    const int kc = c * 64;
#pragma unroll
    for (int i = 0; i < 4; ++i) {
      const float4 v = *reinterpret_cast<const float4*>(
          Xb + (size_t)ms * 2048 + kc + i * 16 + cs);
      *reinterpret_cast<float4*>(&stage[ms * 68 + i * 16 + cs]) = v;
    }
    // wave-private LDS; compiler inserts the vmcnt/lgkmcnt; no barrier.
#pragma unroll
    for (int h = 0; h < 2; ++h) {
      const float4 xlo = *reinterpret_cast<const float4*>(
          &stage[m * 68 + h * 32 + g * 8]);
      const float4 xhi = *reinterpret_cast<const float4*>(
          &stage[m * 68 + h * 32 + g * 8 + 4]);
      bf16x8 afrag;
      afrag[0] = f2bf(xlo.x); afrag[1] = f2bf(xlo.y);
      afrag[2] = f2bf(xlo.z); afrag[3] = f2bf(xlo.w);
      afrag[4] = f2bf(xhi.x); afrag[5] = f2bf(xhi.y);
      afrag[6] = f2bf(xhi.z); afrag[7] = f2bf(xhi.w);
      const bf16x8 bfrag = *reinterpret_cast<const bf16x8*>(
          Ap + (size_t)(c * 2 + h) * 32);
      acc = __builtin_amdgcn_mfma_f32_16x16x32_bf16(afrag, bfrag, acc, 0, 0, 0);
    }
  }

  __syncthreads();                         // all waves done with stage
  float* part = lds;
#pragma unroll
  for (int v = 0; v < 4; ++v)
    part[(wv * 16 + g * 4 + v) * 17 + m] = acc[v];
  __syncthreads();

  const int row = tid >> 4;                // 0..15
  const int r   = tid & 15;
  const float s = part[(0 * 16 + row) * 17 + r] + part[(1 * 16 + row) * 17 + r]
                + part[(2 * 16 + row) * 17 + r] + part[(3 * 16 + row) * 17 + r];
  tmp_p[((size_t)((ks * 8 + b) * 2048 + row0 + row)) * RANK + r] = s;
}

// ---------------------------------------------------------------------------
// Kernel 3 (phase B): thread owns 2 cols -> B-slab 32 VGPR -> ~28 waves/CU
// of store TLP; dwordx2 coalesced stores at ~7 TB/s (write floor).
// Grid 2048 = 8b x 64 rowtiles(32) x 4 colgroups(512).
// ---------------------------------------------------------------------------
__global__ __launch_bounds__(256, 2) void lora_phase_b(
    const float* __restrict__ tmp_p, // [2][8][2048][16] partials
    const float* __restrict__ Bm,    // [8][16][2048] (pre-scaled by 2)
    float* __restrict__ out)         // [8][2048][2048]
{
  const int tid  = threadIdx.x;
  const int b    = blockIdx.x >> 8;          // 8 batches
  const int rt   = (blockIdx.x >> 2) & 63;   // row tile (32 rows)
  const int og   = blockIdx.x & 3;           // column group (512 cols)
  const int row0 = rt * 32;
  const int o0   = og * 512 + tid * 2;

  const float* Bb = Bm + (size_t)b * (RANK * 2048) + o0;
  float2 B2[RANK];
#pragma unroll
  for (int r = 0; r < RANK; ++r)
    B2[r] = *reinterpret_cast<const float2*>(Bb + (size_t)r * 2048);

  const float* tp0 = tmp_p + ((size_t)(b * 2048 + row0)) * RANK;
  const float* tp1 = tmp_p + ((size_t)((8 + b) * 2048 + row0)) * RANK;
  float* op = out + ((size_t)(b * 2048 + row0)) * 2048 + o0;

#pragma unroll 4
  for (int rr = 0; rr < 32; ++rr) {
    const float4 u0 = *reinterpret_cast<const float4*>(tp0 + rr * RANK);
    const float4 u1 = *reinterpret_cast<const float4*>(tp0 + rr * RANK + 4);
    const float4 u2 = *reinterpret_cast<const float4*>(tp0 + rr * RANK + 8);
    const float4 u3 = *reinterpret_cast<const float4*>(tp0 + rr * RANK + 12);
    const float4 v0 = *reinterpret_cast<const float4*>(tp1 + rr * RANK);
    const float4 v1 = *reinterpret_cast<const float4*>(tp1 + rr * RANK + 4);
    const float4 v2 = *reinterpret_cast<const float4*>(tp1 + rr * RANK + 8);
    const float4 v3 = *reinterpret_cast<const float4*>(tp1 + rr * RANK + 12);
    const float t0x = u0.x + v0.x, t0y = u0.y + v0.y, t0z = u0.z + v0.z, t0w = u0.w + v0.w;
    const float t1x = u1.x + v1.x, t1y = u1.y + v1.y, t1z = u1.z + v1.z, t1w = u1.w + v1.w;
    const float t2x = u2.x + v2.x, t2y = u2.y + v2.y, t2z = u2.z + v2.z, t2w = u2.w + v2.w;
    const float t3x = u3.x + v3.x, t3y = u3.y + v3.y, t3z = u3.z + v3.z, t3w = u3.w + v3.w;
    float2 a = make_float2(0.f, 0.f);
    a.x = fmaf(t0x, B2[0].x,  a.x);  a.y = fmaf(t0x, B2[0].y,  a.y);
    a.x = fmaf(t0y, B2[1].x,  a.x);  a.y = fmaf(t0y, B2[1].y,  a.y);
    a.x = fmaf(t0z, B2[2].x,  a.x);  a.y = fmaf(t0z, B2[2].y,  a.y);
    a.x = fmaf(t0w, B2[3].x,  a.x);  a.y = fmaf(t0w, B2[3].y,  a.y);
    a.x = fmaf(t1x, B2[4].x,  a.x);  a.y = fmaf(t1x, B2[4].y,  a.y);
    a.x = fmaf(t1y, B2[5].x,  a.x);  a.y = fmaf(t1y, B2[5].y,  a.y);
    a.x = fmaf(t1z, B2[6].x,  a.x);  a.y = fmaf(t1z, B2[6].y,  a.y);
    a.x = fmaf(t1w, B2[7].x,  a.x);  a.y = fmaf(t1w, B2[7].y,  a.y);
    a.x = fmaf(t2x, B2[8].x,  a.x);  a.y = fmaf(t2x, B2[8].y,  a.y);
    a.x = fmaf(t2y, B2[9].x,  a.x);  a.y = fmaf(t2y, B2[9].y,  a.y);
    a.x = fmaf(t2z, B2[10].x, a.x);  a.y = fmaf(t2z, B2[10].y, a.y);
    a.x = fmaf(t2w, B2[11].x, a.x);  a.y = fmaf(t2w, B2[11].y, a.y);
    a.x = fmaf(t3x, B2[12].x, a.x);  a.y = fmaf(t3x, B2[12].y, a.y);
    a.x = fmaf(t3y, B2[13].x, a.x);  a.y = fmaf(t3y, B2[13].y, a.y);
    a.x = fmaf(t3z, B2[14].x, a.x);  a.y = fmaf(t3z, B2[14].y, a.y);
    a.x = fmaf(t3w, B2[15].x, a.x);  a.y = fmaf(t3w, B2[15].y, a.y);
    *reinterpret_cast<float2*>(op + (size_t)rr * 2048) = a;
  }
}

// ---------------------------------------------------------------------------
extern "C" void kernel_launch(void* const* d_in, const int* in_sizes, int n_in,
                              void* d_out, int out_size, void* d_ws, size_t ws_size,
                              hipStream_t stream) {
  const float* input = (const float*)d_in[0];   // [8][2048][2048]
  const float* w     = (const float*)d_in[1];   // [8][4][8]
  const float* la    = (const float*)d_in[2];   // [4][8][512][16]
  const float* lb    = (const float*)d_in[3];   // [4][8][16][512]
  float* outp = (float*)d_out;

  __hip_bfloat16* Amt = (__hip_bfloat16*)d_ws;                      // 512 KB
  float* Bm    = (float*)((char*)d_ws + (size_t)8 * 16 * 2048 * 2); // 1 MB
  float* tmp_p = Bm + 8 * RANK * 2048;                              // 2 MB

  skilled_lora_mix<<<512, 256, 0, stream>>>(w, la, lb, Amt, Bm);
  lora_phase_a<<<2048, 256, 0, stream>>>(input, Amt, tmp_p);
  lora_phase_b<<<2048, 256, 0, stream>>>(tmp_p, Bm, outp);
}